// Round 14
// baseline (77.710 us; speedup 1.0000x reference)
//
#include <hip/hip_runtime.h>
#include <hip/hip_bf16.h>

// RBF: out[n][o] = exp(-max(||x_n||^2 - 2<x_n,c_o> + ||c_o||^2, 0) * exp(-2*ls_o))
// M=131072, K=128, O=512.
//
// Round-14 = R13 (74.2us, nt full-line stores confirmed the L2-writeback
// bottleneck) + two mechanism-aligned stacks:
//  (1) 2-unit stage slots -> drain bursts of EIGHT back-to-back full-line nt
//      stores (2x per-burst store depth; nt completes at HBM latency so
//      per-wave in-flight coverage was thin at 4/burst).
//  (2) nt loads on x (read-once; stop allocating 67MB into L2, keep it for
//      the frag table).
// Everything else identical to R13: K1 frag pack, XCD swizzle, load-first/
// store-last vmcnt ordering, LDS tables, exp2 epilogue.

typedef __attribute__((ext_vector_type(8))) short bf16x8;
typedef __attribute__((ext_vector_type(4))) float f32x4;
typedef __attribute__((ext_vector_type(4))) unsigned u32x4;

#define KDIM 128
#define ODIM 512
#define LOG2E 1.4426950408889634f

union BF8 { unsigned u[4]; bf16x8 v; u32x4 q; };

// round-to-nearest-even fp32 -> bf16, packed pair
__device__ __forceinline__ unsigned pack_bf2(float a, float b) {
    unsigned ua = __builtin_bit_cast(unsigned, a);
    unsigned ub = __builtin_bit_cast(unsigned, b);
    ua += 0x7fffu + ((ua >> 16) & 1u);
    ub += 0x7fffu + ((ub >> 16) & 1u);
    return (ua >> 16) | (ub & 0xffff0000u);
}

// ---------------- K1: pack centers + tables into ws ----------------
// ws layout: [0,128KiB) frag region: u32x4 index (g*4+kk)*64+l holds bf16x8 of
//            center c=g*16+(l&15), k = kk*32+(l>>4)*8 .. +8
//            [128KiB,+2KiB) wsis = exp(-2*ls)*log2e
//            [130KiB,+2KiB) wscs = csq*exp(-2*ls)*log2e
__global__ __launch_bounds__(256) void rbf_pack_kernel(
    const float* __restrict__ centers,
    const float* __restrict__ log_sigmas,
    u32x4* __restrict__ wsfrag,
    float* __restrict__ wsis,
    float* __restrict__ wscs)
{
    const int b = blockIdx.x;
    if (b < 32) {
        int i  = b * 256 + threadIdx.x;      // 0..8191
        int g  = i >> 8;
        int kk = (i >> 6) & 3;
        int l  = i & 63;
        int c  = g * 16 + (l & 15);
        int k0 = kk * 32 + (l >> 4) * 8;
        const f32x4* p = (const f32x4*)(centers + (size_t)c * KDIM + k0);
        f32x4 v0 = p[0], v1 = p[1];
        BF8 w;
        w.u[0] = pack_bf2(v0.x, v0.y);
        w.u[1] = pack_bf2(v0.z, v0.w);
        w.u[2] = pack_bf2(v1.x, v1.y);
        w.u[3] = pack_bf2(v1.z, v1.w);
        wsfrag[i] = w.q;
    } else {
        int c = (b - 32) * 256 + threadIdx.x;   // 0..511
        const f32x4* p = (const f32x4*)(centers + (size_t)c * KDIM);
        float s = 0.f;
        #pragma unroll
        for (int k = 0; k < 32; ++k) {
            f32x4 v = p[k];
            s += v.x*v.x + v.y*v.y + v.z*v.z + v.w*v.w;
        }
        float a = __expf(-2.0f * log_sigmas[c]) * LOG2E;
        wsis[c] = a;
        wscs[c] = s * a;
    }
}

// ---------------- K2: main kernel ----------------
__global__ __launch_bounds__(256, 4) void rbf_main_kernel(
    const float* __restrict__ x,
    const u32x4* __restrict__ wsfrag,
    const f32x4* __restrict__ wsis4,
    const f32x4* __restrict__ wscs4,
    float* __restrict__ out)
{
    __shared__ f32x4 stage[4][2][32 * 8];  // 32 KiB: per-wave 2 slots x 32r x 128B
    __shared__ float sIS[ODIM];            // 2 KiB
    __shared__ float sCS[ODIM];            // 2 KiB

    const int t  = threadIdx.x;   // 0..255
    const int w  = t >> 6;        // wave 0..3
    const int l  = t & 63;
    const int lr = l & 15;        // x-row within 16-row tile (C/D col)
    const int lk = l >> 4;        // k-group / center sub-block

    // ---- tables -> LDS (keeps vmcnt stream pure in the main loop) ----
    if (t < 128) {
        ((f32x4*)sIS)[t] = wsis4[t];
        ((f32x4*)sCS)[t] = wscs4[t];
    }
    __syncthreads();   // the only barrier

    // ---- XCD-bijective swizzle: XCD i gets blocks i*128..i*128+127 ----
    const int cpx = (int)gridDim.x >> 3;            // 128
    const int bid = (int)blockIdx.x;
    const int wg  = (bid & 7) * cpx + (bid >> 3);
    const int r0  = wg * 128 + w * 32;              // this wave's 32 rows

    // ---- x -> bf16 register fragments (2 x 16-row tiles), NT loads ----
    bf16x8 xf0[4], xf1[4];
    float xsq0, xsq1;
#define LOADX(XF, XS, ROWOFF)                                                  \
    {                                                                          \
        const float* xp = x + (size_t)(r0 + (ROWOFF) + lr) * KDIM + lk * 8;    \
        float s = 0.f;                                                         \
        _Pragma("unroll")                                                      \
        for (int kk = 0; kk < 4; ++kk) {                                       \
            const f32x4* p = (const f32x4*)(xp + kk * 32);                     \
            f32x4 v0 = __builtin_nontemporal_load(p);                          \
            f32x4 v1 = __builtin_nontemporal_load(p + 1);                      \
            s += v0.x*v0.x + v0.y*v0.y + v0.z*v0.z + v0.w*v0.w                 \
               + v1.x*v1.x + v1.y*v1.y + v1.z*v1.z + v1.w*v1.w;                \
            BF8 bw;                                                            \
            bw.u[0] = pack_bf2(v0.x, v0.y);                                    \
            bw.u[1] = pack_bf2(v0.z, v0.w);                                    \
            bw.u[2] = pack_bf2(v1.x, v1.y);                                    \
            bw.u[3] = pack_bf2(v1.z, v1.w);                                    \
            XF[kk] = bw.v;                                                     \
        }                                                                      \
        s += __shfl_xor(s, 16);                                                \
        s += __shfl_xor(s, 32);                                                \
        XS = s;                                                                \
    }
    LOADX(xf0, xsq0, 0)
    LOADX(xf1, xsq1, 16)
#undef LOADX

    const bf16x8* fb = (const bf16x8*)wsfrag + l;   // + (g*4+kk)*64

    // preload group-0 fragments (L2-resident)
    bf16x8 cfA[4], cfB[4];
    cfA[0] = fb[0];
    cfA[1] = fb[64];
    cfA[2] = fb[128];
    cfA[3] = fb[192];

    // one group: prefetch NEXT group's frags FIRST (loads precede this pair's
    // stores), 8 MFMA, epilogue -> P,Q registers. Tables come from LDS.
#define GRP(G, CUR, NXT, P, Q)                                                 \
    {                                                                          \
        const int gn = ((G) + 1) & 31;                                         \
        NXT[0] = fb[gn * 256 + 0];                                             \
        NXT[1] = fb[gn * 256 + 64];                                            \
        NXT[2] = fb[gn * 256 + 128];                                           \
        NXT[3] = fb[gn * 256 + 192];                                           \
        f32x4 a0 = (f32x4){0.f, 0.f, 0.f, 0.f};                                \
        f32x4 a1 = (f32x4){0.f, 0.f, 0.f, 0.f};                                \
        _Pragma("unroll")                                                      \
        for (int kk = 0; kk < 4; ++kk) {                                       \
            a0 = __builtin_amdgcn_mfma_f32_16x16x32_bf16(CUR[kk], xf0[kk], a0, 0, 0, 0); \
            a1 = __builtin_amdgcn_mfma_f32_16x16x32_bf16(CUR[kk], xf1[kk], a1, 0, 0, 0); \
        }                                                                      \
        const int cb = (G) * 16 + lk * 4;                                      \
        f32x4 A4 = *(const f32x4*)&sIS[cb];                                    \
        f32x4 B4 = *(const f32x4*)&sCS[cb];                                    \
        P.x = exp2f(-fmaxf(fmaf(A4.x, fmaf(-2.f, a0[0], xsq0), B4.x), 0.f));   \
        P.y = exp2f(-fmaxf(fmaf(A4.y, fmaf(-2.f, a0[1], xsq0), B4.y), 0.f));   \
        P.z = exp2f(-fmaxf(fmaf(A4.z, fmaf(-2.f, a0[2], xsq0), B4.z), 0.f));   \
        P.w = exp2f(-fmaxf(fmaf(A4.w, fmaf(-2.f, a0[3], xsq0), B4.w), 0.f));   \
        Q.x = exp2f(-fmaxf(fmaf(A4.x, fmaf(-2.f, a1[0], xsq1), B4.x), 0.f));   \
        Q.y = exp2f(-fmaxf(fmaf(A4.y, fmaf(-2.f, a1[1], xsq1), B4.y), 0.f));   \
        Q.z = exp2f(-fmaxf(fmaf(A4.z, fmaf(-2.f, a1[2], xsq1), B4.z), 0.f));   \
        Q.w = exp2f(-fmaxf(fmaf(A4.w, fmaf(-2.f, a1[3], xsq1), B4.w), 0.f));   \
    }

    f32x4 o0, o1, o2, o3;

    // STG(U, SL): groups {2U,2U+1} -> cols U*32..+31 staged into slot SL.
    // Stage swizzle ch^(lr&7): 2-way per 16-lane quarter on both sides (free).
#define STG(U, SL, CA, CB)                                                     \
    GRP(2*(U),     CA, CB, o0, o1)                                             \
    GRP(2*(U) + 1, CB, CA, o2, o3)                                             \
    {                                                                          \
        const int c0 = lk ^ (lr & 7);                                          \
        const int c1 = (4 + lk) ^ (lr & 7);                                    \
        stage[w][SL][lr * 8 + c0]        = o0;                                 \
        stage[w][SL][(16 + lr) * 8 + c0] = o1;                                 \
        stage[w][SL][lr * 8 + c1]        = o2;                                 \
        stage[w][SL][(16 + lr) * 8 + c1] = o3;                                 \
    }

    // PAIR(P): two units staged, then ONE burst of 8 full-line nt stores
    // (cols P*64..P*64+63 of all 32 rows; each instr = 8 rows x 128B lines).
#define PAIR(P)                                                                \
    STG(2*(P),     0, cfA, cfB)                                                \
    STG(2*(P) + 1, 1, cfA, cfB)                                                \
    _Pragma("unroll")                                                          \
    for (int q = 0; q < 8; ++q) {                                              \
        int sl  = q >> 2;                                                      \
        int row = (q & 3) * 8 + (l >> 3);                                      \
        int ch  = l & 7;                                                       \
        f32x4 v = stage[w][sl][row * 8 + (ch ^ (row & 7))];                    \
        __builtin_nontemporal_store(v,                                         \
            (f32x4*)(out + (size_t)(r0 + row) * ODIM + (P) * 64 + sl * 32 + ch * 4)); \
    }

    PAIR(0)  PAIR(1)  PAIR(2)  PAIR(3)
    PAIR(4)  PAIR(5)  PAIR(6)  PAIR(7)
#undef PAIR
#undef STG
#undef GRP
}

// ---------------- fallback (proven ~92us path): used if ws too small ----
__global__ __launch_bounds__(1024, 1) void rbf_fallback_kernel(
    const float* __restrict__ x,
    const float* __restrict__ centers,
    const float* __restrict__ log_sigmas,
    float* __restrict__ out)
{
    __shared__ u32x4 sC[ODIM * 16];
    __shared__ float sIS[ODIM];
    __shared__ float sCS[ODIM];

    const int t  = threadIdx.x;
    const int w  = t >> 6;
    const int l  = t & 63;
    const int lr = l & 15;
    const int lk = l >> 4;

    #pragma unroll
    for (int i = 0; i < 8; ++i) {
        int c    = i * 1024 + t;
        int row  = c >> 4;
        int col8 = c & 15;
        const f32x4* gp = (const f32x4*)(centers + (size_t)row * KDIM + col8 * 8);
        f32x4 v0 = gp[0], v1 = gp[1];
        float s = v0.x*v0.x + v0.y*v0.y + v0.z*v0.z + v0.w*v0.w
                + v1.x*v1.x + v1.y*v1.y + v1.z*v1.z + v1.w*v1.w;
        s += __shfl_xor(s, 1); s += __shfl_xor(s, 2);
        s += __shfl_xor(s, 4); s += __shfl_xor(s, 8);
        BF8 wv;
        wv.u[0] = pack_bf2(v0.x, v0.y);
        wv.u[1] = pack_bf2(v0.z, v0.w);
        wv.u[2] = pack_bf2(v1.x, v1.y);
        wv.u[3] = pack_bf2(v1.z, v1.w);
        int byte = row * 256 + col8 * 16;
        byte ^= (row & 7) << 4;
        *(u32x4*)((char*)sC + byte) = wv.q;
        if ((t & 15) == 0) {
            float a = __expf(-2.0f * log_sigmas[row]);
            sIS[row] = a;
            sCS[row] = s * a;
        }
    }
    __syncthreads();

    const int r0 = blockIdx.x * 512 + w * 32;
    bf16x8 xf[2][4];
    float  xsq[2];
    #pragma unroll
    for (int tt = 0; tt < 2; ++tt) {
        const float* xp = x + (size_t)(r0 + tt * 16 + lr) * KDIM + lk * 8;
        float s = 0.f;
        #pragma unroll
        for (int kk = 0; kk < 4; ++kk) {
            const f32x4* p = (const f32x4*)(xp + kk * 32);
            f32x4 v0 = p[0], v1 = p[1];
            s += v0.x*v0.x + v0.y*v0.y + v0.z*v0.z + v0.w*v0.w
               + v1.x*v1.x + v1.y*v1.y + v1.z*v1.z + v1.w*v1.w;
            BF8 b;
            b.u[0] = pack_bf2(v0.x, v0.y);
            b.u[1] = pack_bf2(v0.z, v0.w);
            b.u[2] = pack_bf2(v1.x, v1.y);
            b.u[3] = pack_bf2(v1.z, v1.w);
            xf[tt][kk] = b.v;
        }
        s += __shfl_xor(s, 16);
        s += __shfl_xor(s, 32);
        xsq[tt] = s;
    }

    float* orow0 = out + (size_t)(r0 + lr) * ODIM;
    float* orow1 = out + (size_t)(r0 + 16 + lr) * ODIM;

    #pragma unroll 2
    for (int g = 0; g < 32; ++g) {
        bf16x8 af[4];
        #pragma unroll
        for (int kk = 0; kk < 4; ++kk) {
            int row  = g * 16 + lr;
            int byte = row * 256 + kk * 64 + lk * 16;
            byte ^= (row & 7) << 4;
            af[kk] = *(const bf16x8*)((const char*)sC + byte);
        }
        f32x4 a0 = (f32x4){0.f, 0.f, 0.f, 0.f};
        f32x4 a1 = (f32x4){0.f, 0.f, 0.f, 0.f};
        #pragma unroll
        for (int kk = 0; kk < 4; ++kk) {
            a0 = __builtin_amdgcn_mfma_f32_16x16x32_bf16(af[kk], xf[0][kk], a0, 0, 0, 0);
            a1 = __builtin_amdgcn_mfma_f32_16x16x32_bf16(af[kk], xf[1][kk], a1, 0, 0, 0);
        }
        const int cb = g * 16 + lk * 4;
        f32x4 A4 = *(const f32x4*)&sIS[cb];
        f32x4 B4 = *(const f32x4*)&sCS[cb];
        f32x4 o0, o1;
        o0.x = __expf(-fmaxf(fmaf(A4.x, fmaf(-2.f, a0[0], xsq[0]), B4.x), 0.f));
        o0.y = __expf(-fmaxf(fmaf(A4.y, fmaf(-2.f, a0[1], xsq[0]), B4.y), 0.f));
        o0.z = __expf(-fmaxf(fmaf(A4.z, fmaf(-2.f, a0[2], xsq[0]), B4.z), 0.f));
        o0.w = __expf(-fmaxf(fmaf(A4.w, fmaf(-2.f, a0[3], xsq[0]), B4.w), 0.f));
        o1.x = __expf(-fmaxf(fmaf(A4.x, fmaf(-2.f, a1[0], xsq[1]), B4.x), 0.f));
        o1.y = __expf(-fmaxf(fmaf(A4.y, fmaf(-2.f, a1[1], xsq[1]), B4.y), 0.f));
        o1.z = __expf(-fmaxf(fmaf(A4.z, fmaf(-2.f, a1[2], xsq[1]), B4.z), 0.f));
        o1.w = __expf(-fmaxf(fmaf(A4.w, fmaf(-2.f, a1[3], xsq[1]), B4.w), 0.f));
        *(f32x4*)(orow0 + cb) = o0;
        *(f32x4*)(orow1 + cb) = o1;
    }
}

extern "C" void kernel_launch(void* const* d_in, const int* in_sizes, int n_in,
                              void* d_out, int out_size, void* d_ws, size_t ws_size,
                              hipStream_t stream) {
    const float* x          = (const float*)d_in[0];
    const float* centers    = (const float*)d_in[1];
    const float* log_sigmas = (const float*)d_in[2];
    float* out = (float*)d_out;

    const int n_rows = in_sizes[0] / KDIM;   // 131072

    // ws layout: 128KiB frags + 2KiB wsis + 2KiB wscs
    const size_t WS_NEED = 128 * 1024 + 2 * 2048;
    if (ws_size >= WS_NEED && (n_rows / 128) % 8 == 0) {
        u32x4* wsfrag = (u32x4*)d_ws;
        float* wsis   = (float*)((char*)d_ws + 128 * 1024);
        float* wscs   = (float*)((char*)d_ws + 128 * 1024 + 2048);
        rbf_pack_kernel<<<34, 256, 0, stream>>>(centers, log_sigmas,
                                                wsfrag, wsis, wscs);
        rbf_main_kernel<<<n_rows / 128, 256, 0, stream>>>(
            x, wsfrag, (const f32x4*)wsis, (const f32x4*)wscs, out);
    } else {
        rbf_fallback_kernel<<<n_rows / 512, 1024, 0, stream>>>(
            x, centers, log_sigmas, out);
    }
}

// Round 15
// 73.771 us; speedup vs baseline: 1.0534x; 1.0534x over previous
//
#include <hip/hip_runtime.h>
#include <hip/hip_bf16.h>

// RBF: out[n][o] = exp(-max(||x_n||^2 - 2<x_n,c_o> + ||c_o||^2, 0) * exp(-2*ls_o))
// M=131072, K=128, O=512.
//
// Round-15 = R13 (74.2us champion) + ONE change: drain-REGISTER ROTATION.
// gfx9 VMEM-WAR hazard: redefining a VGPR used by a pending store forces
// s_waitcnt vmcnt(N). R13's drain reused the same 4 temps every unit ->
// forced full drain of the previous unit's 4 nt stores every ~330cy, capping
// per-wave outstanding nt stores at ~4 (nt completes at HBM latency ~900cy).
// Now two disjoint sets (d0-3 / e0-3) alternate across units -> reuse
// distance ~660cy, half the forced drains. Everything else = R13 verbatim.

typedef __attribute__((ext_vector_type(8))) short bf16x8;
typedef __attribute__((ext_vector_type(4))) float f32x4;
typedef __attribute__((ext_vector_type(4))) unsigned u32x4;

#define KDIM 128
#define ODIM 512
#define LOG2E 1.4426950408889634f

union BF8 { unsigned u[4]; bf16x8 v; u32x4 q; };

// round-to-nearest-even fp32 -> bf16, packed pair
__device__ __forceinline__ unsigned pack_bf2(float a, float b) {
    unsigned ua = __builtin_bit_cast(unsigned, a);
    unsigned ub = __builtin_bit_cast(unsigned, b);
    ua += 0x7fffu + ((ua >> 16) & 1u);
    ub += 0x7fffu + ((ub >> 16) & 1u);
    return (ua >> 16) | (ub & 0xffff0000u);
}

// ---------------- K1: pack centers + tables into ws ----------------
// ws layout: [0,128KiB) frag region: u32x4 index (g*4+kk)*64+l holds bf16x8 of
//            center c=g*16+(l&15), k = kk*32+(l>>4)*8 .. +8
//            [128KiB,+2KiB) wsis = exp(-2*ls)*log2e
//            [130KiB,+2KiB) wscs = csq*exp(-2*ls)*log2e
__global__ __launch_bounds__(256) void rbf_pack_kernel(
    const float* __restrict__ centers,
    const float* __restrict__ log_sigmas,
    u32x4* __restrict__ wsfrag,
    float* __restrict__ wsis,
    float* __restrict__ wscs)
{
    const int b = blockIdx.x;
    if (b < 32) {
        int i  = b * 256 + threadIdx.x;      // 0..8191
        int g  = i >> 8;
        int kk = (i >> 6) & 3;
        int l  = i & 63;
        int c  = g * 16 + (l & 15);
        int k0 = kk * 32 + (l >> 4) * 8;
        const f32x4* p = (const f32x4*)(centers + (size_t)c * KDIM + k0);
        f32x4 v0 = p[0], v1 = p[1];
        BF8 w;
        w.u[0] = pack_bf2(v0.x, v0.y);
        w.u[1] = pack_bf2(v0.z, v0.w);
        w.u[2] = pack_bf2(v1.x, v1.y);
        w.u[3] = pack_bf2(v1.z, v1.w);
        wsfrag[i] = w.q;
    } else {
        int c = (b - 32) * 256 + threadIdx.x;   // 0..511
        const f32x4* p = (const f32x4*)(centers + (size_t)c * KDIM);
        float s = 0.f;
        #pragma unroll
        for (int k = 0; k < 32; ++k) {
            f32x4 v = p[k];
            s += v.x*v.x + v.y*v.y + v.z*v.z + v.w*v.w;
        }
        float a = __expf(-2.0f * log_sigmas[c]) * LOG2E;
        wsis[c] = a;
        wscs[c] = s * a;
    }
}

// ---------------- K2: main kernel ----------------
__global__ __launch_bounds__(256, 4) void rbf_main_kernel(
    const float* __restrict__ x,
    const u32x4* __restrict__ wsfrag,
    const f32x4* __restrict__ wsis4,
    const f32x4* __restrict__ wscs4,
    float* __restrict__ out)
{
    __shared__ f32x4 stage[4][32 * 8];   // 16 KiB: per-wave 32 rows x 128B
    __shared__ float sIS[ODIM];          // 2 KiB
    __shared__ float sCS[ODIM];          // 2 KiB

    const int t  = threadIdx.x;   // 0..255
    const int w  = t >> 6;        // wave 0..3
    const int l  = t & 63;
    const int lr = l & 15;        // x-row within 16-row tile (C/D col)
    const int lk = l >> 4;        // k-group / center sub-block

    // ---- tables -> LDS (keeps vmcnt stream pure in the main loop) ----
    if (t < 128) {
        ((f32x4*)sIS)[t] = wsis4[t];
        ((f32x4*)sCS)[t] = wscs4[t];
    }
    __syncthreads();   // the only barrier

    // ---- XCD-bijective swizzle: XCD i gets blocks i*128..i*128+127 ----
    const int cpx = (int)gridDim.x >> 3;            // 128
    const int bid = (int)blockIdx.x;
    const int wg  = (bid & 7) * cpx + (bid >> 3);
    const int r0  = wg * 128 + w * 32;              // this wave's 32 rows

    // ---- x -> bf16 register fragments (2 x 16-row tiles) ----
    bf16x8 xf0[4], xf1[4];
    float xsq0, xsq1;
#define LOADX(XF, XS, ROWOFF)                                                  \
    {                                                                          \
        const float* xp = x + (size_t)(r0 + (ROWOFF) + lr) * KDIM + lk * 8;    \
        float s = 0.f;                                                         \
        _Pragma("unroll")                                                      \
        for (int kk = 0; kk < 4; ++kk) {                                       \
            const f32x4* p = (const f32x4*)(xp + kk * 32);                     \
            f32x4 v0 = p[0], v1 = p[1];                                        \
            s += v0.x*v0.x + v0.y*v0.y + v0.z*v0.z + v0.w*v0.w                 \
               + v1.x*v1.x + v1.y*v1.y + v1.z*v1.z + v1.w*v1.w;                \
            BF8 bw;                                                            \
            bw.u[0] = pack_bf2(v0.x, v0.y);                                    \
            bw.u[1] = pack_bf2(v0.z, v0.w);                                    \
            bw.u[2] = pack_bf2(v1.x, v1.y);                                    \
            bw.u[3] = pack_bf2(v1.z, v1.w);                                    \
            XF[kk] = bw.v;                                                     \
        }                                                                      \
        s += __shfl_xor(s, 16);                                                \
        s += __shfl_xor(s, 32);                                                \
        XS = s;                                                                \
    }
    LOADX(xf0, xsq0, 0)
    LOADX(xf1, xsq1, 16)
#undef LOADX

    f32x4* st = &stage[w][0];                       // wave-private
    const bf16x8* fb = (const bf16x8*)wsfrag + l;   // + (g*4+kk)*64

    // preload group-0 fragments (L2-resident)
    bf16x8 cfA[4], cfB[4];
    cfA[0] = fb[0];
    cfA[1] = fb[64];
    cfA[2] = fb[128];
    cfA[3] = fb[192];

    // one group: prefetch NEXT group's frags FIRST (loads precede this unit's
    // stores), 8 MFMA, epilogue -> P,Q registers. Tables come from LDS.
#define GRP(G, CUR, NXT, P, Q)                                                 \
    {                                                                          \
        const int gn = ((G) + 1) & 31;                                         \
        NXT[0] = fb[gn * 256 + 0];                                             \
        NXT[1] = fb[gn * 256 + 64];                                            \
        NXT[2] = fb[gn * 256 + 128];                                           \
        NXT[3] = fb[gn * 256 + 192];                                           \
        f32x4 a0 = (f32x4){0.f, 0.f, 0.f, 0.f};                                \
        f32x4 a1 = (f32x4){0.f, 0.f, 0.f, 0.f};                                \
        _Pragma("unroll")                                                      \
        for (int kk = 0; kk < 4; ++kk) {                                       \
            a0 = __builtin_amdgcn_mfma_f32_16x16x32_bf16(CUR[kk], xf0[kk], a0, 0, 0, 0); \
            a1 = __builtin_amdgcn_mfma_f32_16x16x32_bf16(CUR[kk], xf1[kk], a1, 0, 0, 0); \
        }                                                                      \
        const int cb = (G) * 16 + lk * 4;                                      \
        f32x4 A4 = *(const f32x4*)&sIS[cb];                                    \
        f32x4 B4 = *(const f32x4*)&sCS[cb];                                    \
        P.x = exp2f(-fmaxf(fmaf(A4.x, fmaf(-2.f, a0[0], xsq0), B4.x), 0.f));   \
        P.y = exp2f(-fmaxf(fmaf(A4.y, fmaf(-2.f, a0[1], xsq0), B4.y), 0.f));   \
        P.z = exp2f(-fmaxf(fmaf(A4.z, fmaf(-2.f, a0[2], xsq0), B4.z), 0.f));   \
        P.w = exp2f(-fmaxf(fmaf(A4.w, fmaf(-2.f, a0[3], xsq0), B4.w), 0.f));   \
        Q.x = exp2f(-fmaxf(fmaf(A4.x, fmaf(-2.f, a1[0], xsq1), B4.x), 0.f));   \
        Q.y = exp2f(-fmaxf(fmaf(A4.y, fmaf(-2.f, a1[1], xsq1), B4.y), 0.f));   \
        Q.z = exp2f(-fmaxf(fmaf(A4.z, fmaf(-2.f, a1[2], xsq1), B4.z), 0.f));   \
        Q.w = exp2f(-fmaxf(fmaf(A4.w, fmaf(-2.f, a1[3], xsq1), B4.w), 0.f));   \
    }

    f32x4 o0, o1, o2, o3;
    // two disjoint drain-register sets, alternated across units (VMEM-WAR fix)
    f32x4 d0, d1, d2, d3, e0, e1, e2, e3;

    // unit U = groups {2U, 2U+1} -> cols U*32..U*32+31 of all 32 rows.
    // loads first ... compute ... ds stage ... drain into V0..V3 (this unit's
    // register set) ... 4 full-line nt stores LAST.
#define UNIT(U, CA, CB, V0, V1, V2, V3)                                        \
    GRP(2*(U),     CA, CB, o0, o1)                                             \
    GRP(2*(U) + 1, CB, CA, o2, o3)                                             \
    {                                                                          \
        const int c0 = lk ^ (lr & 7);                                          \
        const int c1 = (4 + lk) ^ (lr & 7);                                    \
        st[lr * 8 + c0]        = o0;                                           \
        st[(16 + lr) * 8 + c0] = o1;                                           \
        st[lr * 8 + c1]        = o2;                                           \
        st[(16 + lr) * 8 + c1] = o3;                                           \
        const int rbase = l >> 3;                                              \
        const int ch    = l & 7;                                               \
        V0 = st[(rbase +  0) * 8 + (ch ^ ((rbase +  0) & 7))];                 \
        V1 = st[(rbase +  8) * 8 + (ch ^ ((rbase +  8) & 7))];                 \
        V2 = st[(rbase + 16) * 8 + (ch ^ ((rbase + 16) & 7))];                 \
        V3 = st[(rbase + 24) * 8 + (ch ^ ((rbase + 24) & 7))];                 \
        float* ob = out + (size_t)(r0 + rbase) * ODIM + (U) * 32 + ch * 4;     \
        __builtin_nontemporal_store(V0, (f32x4*)(ob));                         \
        __builtin_nontemporal_store(V1, (f32x4*)(ob +  8 * ODIM));             \
        __builtin_nontemporal_store(V2, (f32x4*)(ob + 16 * ODIM));             \
        __builtin_nontemporal_store(V3, (f32x4*)(ob + 24 * ODIM));             \
    }

    UNIT(0,  cfA, cfB, d0, d1, d2, d3)  UNIT(1,  cfA, cfB, e0, e1, e2, e3)
    UNIT(2,  cfA, cfB, d0, d1, d2, d3)  UNIT(3,  cfA, cfB, e0, e1, e2, e3)
    UNIT(4,  cfA, cfB, d0, d1, d2, d3)  UNIT(5,  cfA, cfB, e0, e1, e2, e3)
    UNIT(6,  cfA, cfB, d0, d1, d2, d3)  UNIT(7,  cfA, cfB, e0, e1, e2, e3)
    UNIT(8,  cfA, cfB, d0, d1, d2, d3)  UNIT(9,  cfA, cfB, e0, e1, e2, e3)
    UNIT(10, cfA, cfB, d0, d1, d2, d3)  UNIT(11, cfA, cfB, e0, e1, e2, e3)
    UNIT(12, cfA, cfB, d0, d1, d2, d3)  UNIT(13, cfA, cfB, e0, e1, e2, e3)
    UNIT(14, cfA, cfB, d0, d1, d2, d3)  UNIT(15, cfA, cfB, e0, e1, e2, e3)
#undef UNIT
#undef GRP
}

// ---------------- fallback (proven path): used if ws too small ----------------
__global__ __launch_bounds__(1024, 1) void rbf_fallback_kernel(
    const float* __restrict__ x,
    const float* __restrict__ centers,
    const float* __restrict__ log_sigmas,
    float* __restrict__ out)
{
    __shared__ u32x4 sC[ODIM * 16];
    __shared__ float sIS[ODIM];
    __shared__ float sCS[ODIM];

    const int t  = threadIdx.x;
    const int w  = t >> 6;
    const int l  = t & 63;
    const int lr = l & 15;
    const int lk = l >> 4;

    #pragma unroll
    for (int i = 0; i < 8; ++i) {
        int c    = i * 1024 + t;
        int row  = c >> 4;
        int col8 = c & 15;
        const f32x4* gp = (const f32x4*)(centers + (size_t)row * KDIM + col8 * 8);
        f32x4 v0 = gp[0], v1 = gp[1];
        float s = v0.x*v0.x + v0.y*v0.y + v0.z*v0.z + v0.w*v0.w
                + v1.x*v1.x + v1.y*v1.y + v1.z*v1.z + v1.w*v1.w;
        s += __shfl_xor(s, 1); s += __shfl_xor(s, 2);
        s += __shfl_xor(s, 4); s += __shfl_xor(s, 8);
        BF8 wv;
        wv.u[0] = pack_bf2(v0.x, v0.y);
        wv.u[1] = pack_bf2(v0.z, v0.w);
        wv.u[2] = pack_bf2(v1.x, v1.y);
        wv.u[3] = pack_bf2(v1.z, v1.w);
        int byte = row * 256 + col8 * 16;
        byte ^= (row & 7) << 4;
        *(u32x4*)((char*)sC + byte) = wv.q;
        if ((t & 15) == 0) {
            float a = __expf(-2.0f * log_sigmas[row]);
            sIS[row] = a;
            sCS[row] = s * a;
        }
    }
    __syncthreads();

    const int r0 = blockIdx.x * 512 + w * 32;
    bf16x8 xf[2][4];
    float  xsq[2];
    #pragma unroll
    for (int tt = 0; tt < 2; ++tt) {
        const float* xp = x + (size_t)(r0 + tt * 16 + lr) * KDIM + lk * 8;
        float s = 0.f;
        #pragma unroll
        for (int kk = 0; kk < 4; ++kk) {
            const f32x4* p = (const f32x4*)(xp + kk * 32);
            f32x4 v0 = p[0], v1 = p[1];
            s += v0.x*v0.x + v0.y*v0.y + v0.z*v0.z + v0.w*v0.w
               + v1.x*v1.x + v1.y*v1.y + v1.z*v1.z + v1.w*v1.w;
            BF8 b;
            b.u[0] = pack_bf2(v0.x, v0.y);
            b.u[1] = pack_bf2(v0.z, v0.w);
            b.u[2] = pack_bf2(v1.x, v1.y);
            b.u[3] = pack_bf2(v1.z, v1.w);
            xf[tt][kk] = b.v;
        }
        s += __shfl_xor(s, 16);
        s += __shfl_xor(s, 32);
        xsq[tt] = s;
    }

    float* orow0 = out + (size_t)(r0 + lr) * ODIM;
    float* orow1 = out + (size_t)(r0 + 16 + lr) * ODIM;

    #pragma unroll 2
    for (int g = 0; g < 32; ++g) {
        bf16x8 af[4];
        #pragma unroll
        for (int kk = 0; kk < 4; ++kk) {
            int row  = g * 16 + lr;
            int byte = row * 256 + kk * 64 + lk * 16;
            byte ^= (row & 7) << 4;
            af[kk] = *(const bf16x8*)((const char*)sC + byte);
        }
        f32x4 a0 = (f32x4){0.f, 0.f, 0.f, 0.f};
        f32x4 a1 = (f32x4){0.f, 0.f, 0.f, 0.f};
        #pragma unroll
        for (int kk = 0; kk < 4; ++kk) {
            a0 = __builtin_amdgcn_mfma_f32_16x16x32_bf16(af[kk], xf[0][kk], a0, 0, 0, 0);
            a1 = __builtin_amdgcn_mfma_f32_16x16x32_bf16(af[kk], xf[1][kk], a1, 0, 0, 0);
        }
        const int cb = g * 16 + lk * 4;
        f32x4 A4 = *(const f32x4*)&sIS[cb];
        f32x4 B4 = *(const f32x4*)&sCS[cb];
        f32x4 o0, o1;
        o0.x = __expf(-fmaxf(fmaf(A4.x, fmaf(-2.f, a0[0], xsq[0]), B4.x), 0.f));
        o0.y = __expf(-fmaxf(fmaf(A4.y, fmaf(-2.f, a0[1], xsq[0]), B4.y), 0.f));
        o0.z = __expf(-fmaxf(fmaf(A4.z, fmaf(-2.f, a0[2], xsq[0]), B4.z), 0.f));
        o0.w = __expf(-fmaxf(fmaf(A4.w, fmaf(-2.f, a0[3], xsq[0]), B4.w), 0.f));
        o1.x = __expf(-fmaxf(fmaf(A4.x, fmaf(-2.f, a1[0], xsq[1]), B4.x), 0.f));
        o1.y = __expf(-fmaxf(fmaf(A4.y, fmaf(-2.f, a1[1], xsq[1]), B4.y), 0.f));
        o1.z = __expf(-fmaxf(fmaf(A4.z, fmaf(-2.f, a1[2], xsq[1]), B4.z), 0.f));
        o1.w = __expf(-fmaxf(fmaf(A4.w, fmaf(-2.f, a1[3], xsq[1]), B4.w), 0.f));
        *(f32x4*)(orow0 + cb) = o0;
        *(f32x4*)(orow1 + cb) = o1;
    }
}

extern "C" void kernel_launch(void* const* d_in, const int* in_sizes, int n_in,
                              void* d_out, int out_size, void* d_ws, size_t ws_size,
                              hipStream_t stream) {
    const float* x          = (const float*)d_in[0];
    const float* centers    = (const float*)d_in[1];
    const float* log_sigmas = (const float*)d_in[2];
    float* out = (float*)d_out;

    const int n_rows = in_sizes[0] / KDIM;   // 131072

    // ws layout: 128KiB frags + 2KiB wsis + 2KiB wscs
    const size_t WS_NEED = 128 * 1024 + 2 * 2048;
    if (ws_size >= WS_NEED && (n_rows / 128) % 8 == 0) {
        u32x4* wsfrag = (u32x4*)d_ws;
        float* wsis   = (float*)((char*)d_ws + 128 * 1024);
        float* wscs   = (float*)((char*)d_ws + 128 * 1024 + 2048);
        rbf_pack_kernel<<<34, 256, 0, stream>>>(centers, log_sigmas,
                                                wsfrag, wsis, wscs);
        rbf_main_kernel<<<n_rows / 128, 256, 0, stream>>>(
            x, wsfrag, (const f32x4*)wsis, (const f32x4*)wscs, out);
    } else {
        rbf_fallback_kernel<<<n_rows / 512, 1024, 0, stream>>>(
            x, centers, log_sigmas, out);
    }
}